// Round 6
// baseline (1017.723 us; speedup 1.0000x reference)
//
#include <hip/hip_runtime.h>
#include <cstdint>

#define B_ 32
#define T_ 40
#define P_ 12
#define E_ 2048
#define H_ 1024
#define BP 384      // B_*P_
#define M_ 15360    // B_*T_*P_

typedef _Float16 f16;
typedef _Float16 f16x8 __attribute__((ext_vector_type(8)));
typedef float f32x4 __attribute__((ext_vector_type(4)));

// ---- async global->LDS, 16B per lane (dest = wave-uniform base + lane*16) ----
__device__ __forceinline__ void cp16(const void* g, void* l) {
    auto gp = (const __attribute__((address_space(1))) uint32_t*)(uintptr_t)g;
    auto lp = (__attribute__((address_space(3))) uint32_t*)(uint32_t)(uintptr_t)l;
    __builtin_amdgcn_global_load_lds(gp, lp, 16, 0, 0);
}

__device__ __forceinline__ float fast_tanh(float x) {
    return 1.f - 2.f / (__expf(2.f * x) + 1.f);
}
__device__ __forceinline__ float fast_sig(float x) {
    return 1.f / (1.f + __expf(-x));
}

// ---- fused fp32 -> fp16 conversion of all four inputs (one launch) ----
#define CVT_N0 ((M_ * E_) / 8)
#define CVT_N1 (CVT_N0 + (H_ * E_) / 8)
#define CVT_N2 (CVT_N1 + (3 * H_ * H_) / 8)
#define CVT_N3 (CVT_N2 + (3 * H_ * H_) / 8)
__global__ __launch_bounds__(256) void cvt_all(const float* __restrict__ f,
                                               const float* __restrict__ we,
                                               const float* __restrict__ wih,
                                               const float* __restrict__ whh,
                                               f16* __restrict__ fo, f16* __restrict__ weo,
                                               f16* __restrict__ wiho, f16* __restrict__ whho) {
    int i = blockIdx.x * 256 + threadIdx.x;
    if (i >= CVT_N3) return;
    const float* src; f16* dst; int j;
    if (i < CVT_N0)      { src = f;   dst = fo;   j = i; }
    else if (i < CVT_N1) { src = we;  dst = weo;  j = i - CVT_N0; }
    else if (i < CVT_N2) { src = wih; dst = wiho; j = i - CVT_N1; }
    else                 { src = whh; dst = whho; j = i - CVT_N2; }
    const float4* in4 = (const float4*)src;
    float4 a = in4[2 * j], b = in4[2 * j + 1];
    f16x8 o = {(f16)a.x, (f16)a.y, (f16)a.z, (f16)a.w,
               (f16)b.x, (f16)b.y, (f16)b.z, (f16)b.w};
    ((f16x8*)dst)[j] = o;
}

// ---- 128x128 tile NT-GEMM, 2-phase double-buffered LDS ----
template <int EPI>
__global__ __launch_bounds__(256) void gemm128(const f16* __restrict__ A,
                                               const f16* __restrict__ Bm,
                                               const float* __restrict__ bias,
                                               f16* __restrict__ out, int K, int N) {
    __shared__ f16 As[2][128 * 32];
    __shared__ f16 Bs[2][128 * 32];
    const int tid = threadIdx.x;
    const int w = tid >> 6, l = tid & 63;
    const int wm = w >> 1, wn = w & 1;      // 2x2 waves of 64x64
    const long arow0 = (long)blockIdx.x * 128;
    const long brow0 = (long)blockIdx.y * 128;
    const int srow = l >> 2, scol = (l & 3) * 8;

    const f16* aptr = A + (arow0 + srow) * (long)K + scol;
    const f16* bptr = Bm + (brow0 + srow) * (long)K + scol;

    f32x4 acc[4][4] = {};

    // prologue: stage tile 0
#pragma unroll
    for (int s = 0; s < 2; ++s) {
        int slice = w + s * 4;              // wave-uniform
        cp16(aptr + (long)slice * 16 * K, (void*)(As[0] + slice * 512));
        cp16(bptr + (long)slice * 16 * K, (void*)(Bs[0] + slice * 512));
    }
    asm volatile("s_waitcnt vmcnt(0)" ::: "memory");
    __syncthreads();

    const int nt = K >> 5;
    for (int t = 0; t < nt; ++t) {
        const int cur = t & 1;
        if (t + 1 < nt) {                   // stage next tile; in flight during MFMA
            const long k0 = (long)(t + 1) << 5;
#pragma unroll
            for (int s = 0; s < 2; ++s) {
                int slice = w + s * 4;
                cp16(aptr + (long)slice * 16 * K + k0, (void*)(As[cur ^ 1] + slice * 512));
                cp16(bptr + (long)slice * 16 * K + k0, (void*)(Bs[cur ^ 1] + slice * 512));
            }
        }
        f16x8 af[4], bf[4];
#pragma unroll
        for (int i = 0; i < 4; ++i)
            af[i] = *(const f16x8*)(As[cur] + (wm * 64 + i * 16 + (l & 15)) * 32 + (l >> 4) * 8);
#pragma unroll
        for (int j = 0; j < 4; ++j)
            bf[j] = *(const f16x8*)(Bs[cur] + (wn * 64 + j * 16 + (l & 15)) * 32 + (l >> 4) * 8);
#pragma unroll
        for (int i = 0; i < 4; ++i)
#pragma unroll
            for (int j = 0; j < 4; ++j)
                acc[i][j] = __builtin_amdgcn_mfma_f32_16x16x32_f16(af[i], bf[j], acc[i][j], 0, 0, 0);
        // one drain+barrier per K-step (next tile's loads complete during compute)
        asm volatile("s_waitcnt vmcnt(0)" ::: "memory");
        __syncthreads();
    }

    const int colq = l & 15, rowq = (l >> 4) * 4;
#pragma unroll
    for (int i = 0; i < 4; ++i)
#pragma unroll
        for (int j = 0; j < 4; ++j)
#pragma unroll
            for (int r = 0; r < 4; ++r) {
                long m = arow0 + wm * 64 + i * 16 + rowq + r;
                int n = (int)brow0 + wn * 64 + j * 16 + colq;
                float v = acc[i][j][r] + bias[n];
                if (EPI == 0) {
                    out[m * N + n] = (f16)fast_tanh(v);
                } else {
                    int b = (int)(m / (T_ * P_));
                    int rem = (int)(m % (T_ * P_));
                    int t = rem / P_, p = rem % P_;
                    out[((long)t * BP + b * P_ + p) * N + n] = (f16)v;
                }
            }
}

// ---- fallback per-step GRU kernel (used only if cooperative launch fails) ----
__global__ __launch_bounds__(256) void gru_step(const f16* __restrict__ h16_in,
                                                f16* __restrict__ h16_out,
                                                float* __restrict__ h32,
                                                const f16* __restrict__ Whh,
                                                const float* __restrict__ b_hh,
                                                const f16* __restrict__ gx16,
                                                f16* __restrict__ hid16, int t) {
    __shared__ f16 As[32 * 32];
    __shared__ f16 Bs[3 * 64 * 32];
    const int tid = threadIdx.x;
    const int w = tid >> 6, l = tid & 63;
    const int m0 = blockIdx.x * 32, n0 = blockIdx.y * 64;
    const int srow = l >> 2, scol = (l & 3) * 8;

    f32x4 acc[3][2] = {};

    for (int k0 = 0; k0 < H_; k0 += 32) {
        __syncthreads();
        if (w < 2)
            cp16(h16_in + (m0 + w * 16 + srow) * H_ + k0 + scol, (void*)(As + w * 512));
#pragma unroll
        for (int q3 = 0; q3 < 3; ++q3) {
            int s = w + q3 * 4;
            int g = s >> 2, q = s & 3;
            cp16(Whh + (long)(g * H_ + n0 + q * 16 + srow) * H_ + k0 + scol,
                 (void*)(Bs + (g * 64 + q * 16) * 32));
        }
        __syncthreads();
        f16x8 af[2], bf[3];
#pragma unroll
        for (int i = 0; i < 2; ++i)
            af[i] = *(const f16x8*)(As + (i * 16 + (l & 15)) * 32 + (l >> 4) * 8);
#pragma unroll
        for (int g = 0; g < 3; ++g)
            bf[g] = *(const f16x8*)(Bs + (g * 64 + w * 16 + (l & 15)) * 32 + (l >> 4) * 8);
#pragma unroll
        for (int g = 0; g < 3; ++g)
#pragma unroll
            for (int i = 0; i < 2; ++i)
                acc[g][i] = __builtin_amdgcn_mfma_f32_16x16x32_f16(af[i], bf[g], acc[g][i], 0, 0, 0);
    }

    const int col = n0 + w * 16 + (l & 15);
    const long gxbase = (long)t * BP * 3072;
    const float bhr = b_hh[col], bhz = b_hh[H_ + col], bhn = b_hh[2 * H_ + col];
#pragma unroll
    for (int i = 0; i < 2; ++i)
#pragma unroll
        for (int r = 0; r < 4; ++r) {
            int m = m0 + i * 16 + (l >> 4) * 4 + r;
            float hr = acc[0][i][r] + bhr;
            float hz = acc[1][i][r] + bhz;
            float hn = acc[2][i][r] + bhn;
            long gxrow = gxbase + (long)m * 3072;
            float xr = (float)gx16[gxrow + col];
            float xz = (float)gx16[gxrow + H_ + col];
            float xn = (float)gx16[gxrow + 2 * H_ + col];
            float rr = fast_sig(xr + hr);
            float zz = fast_sig(xz + hz);
            float nn = fast_tanh(xn + rr * hn);
            float hp = h32[m * H_ + col];
            float hnew = (1.f - zz) * nn + zz * hp;
            h32[m * H_ + col] = hnew;
            h16_out[m * H_ + col] = (f16)hnew;
            int b = m / P_, p = m % P_;
            hid16[(((long)b * T_ + t) * P_ + p) * H_ + col] = (f16)hnew;
        }
}

// ================= persistent GRU: all 40 steps in one cooperative launch =======
// 256 blocks x 384 threads (6 waves, 1 block/CU). Block owns 96 h-rows x 16 h-cols.
// Per-row-group flag barrier (64 producers) instead of grid.sync (round-4 path,
// measured 10.3us/step). This round: the A (h) operand is loaded DIRECTLY from
// hid16 into registers in MFMA fragment layout (one row per lane, 32 x f16x8 at
// immediate offsets) -- no cp16, no A-LDS, no per-iter lgkmcnt(0) drain, no A bank
// conflicts, all 32 loads in flight with compiler-counted vmcnt. LDS = W_hh only.
#define GRU_GRID 256
#define GRU_THREADS 384
#define GRU_LDS (48 * 1024 * 2)              // 98304 B  W_hh slice only
#define FLAG_STRIDE 16                        // ints; 64B per flag

__global__ __launch_bounds__(GRU_THREADS) void gru_persistent(
        const f16* __restrict__ Whh, const float* __restrict__ bhh,
        const f16* __restrict__ gx16, f16* __restrict__ hid16,
        int* __restrict__ flags) {
    extern __shared__ char lds[];

    const int tid = threadIdx.x;
    const int w = tid >> 6, l = tid & 63;
    const int q = l >> 4;

    // XCD row-affinity: blocks on one XCD (bid&7) share the same 96 h-rows
    const int bid = blockIdx.x;
    const int x = bid & 7;
    const int rg = x >> 1;                        // 0..3 row-group, 2 XCDs each
    const int nb = (x & 1) * 32 + (bid >> 3);     // 0..63 col-group
    const int m0 = rg * 96;
    const int j0 = nb * 16;

    // ---- one-time: W_hh slice -> LDS, swizzled (byte ^= (row&7)<<4) ----
    for (int c = tid; c < 6144; c += GRU_THREADS) {
        int r = c >> 7;                  // local row 0..47 = g*16 + jr
        int kc = (c & 127) * 8;          // f16 col
        int grow = (r >> 4) * H_ + j0 + (r & 15);
        f16x8 v = *(const f16x8*)(Whh + (long)grow * H_ + kc);
        *(f16x8*)(lds + r * 2048 + ((kc * 2) ^ ((r & 7) << 4))) = v;
    }

    // ---- per-thread constant offsets ----
    int b_off[3][2];
#pragma unroll
    for (int sub = 0; sub < 2; ++sub)
#pragma unroll
        for (int g = 0; g < 3; ++g) {
            int br = g * 16 + (l & 15);
            b_off[g][sub] = br * 2048 + (((sub * 32 + q * 8) * 2) ^ ((br & 7) << 4));
        }

    // A-fragment source: this lane reads ONE hid16 row (mA) at cols q*8 + kk*64 + sub*32
    const int mA = m0 + w * 16 + (l & 15);
    const long arow_base = ((long)(mA / P_) * (T_ * P_) + (mA % P_)) * H_ + q * 8;

    const int col = j0 + (l & 15);
    const float bhr = bhh[col], bhz = bhh[H_ + col], bhn = bhh[2 * H_ + col];
    const int mrow = m0 + w * 16 + q * 4;
    // hid16 destination rows for this thread's 4 outputs
    long dstrow[4];
#pragma unroll
    for (int r = 0; r < 4; ++r) {
        int m = mrow + r;
        dstrow[r] = ((long)(m / P_) * T_ * P_ + (m % P_)) * H_ + col;
    }

    // persistent fp32 h state (this thread owns rows mrow..mrow+3 at column col)
    float hval[4] = {0.f, 0.f, 0.f, 0.f};

    // gx prefetch registers for step 0
    f16 pgr[4], pgz[4], pgn[4];
#pragma unroll
    for (int r = 0; r < 4; ++r) {
        const long row = (long)(mrow + r) * 3072 + col;
        pgr[r] = gx16[row];
        pgz[r] = gx16[row + H_];
        pgn[r] = gx16[row + 2 * H_];
    }
    __syncthreads();   // W_hh staged, gx(0) in regs

    for (int t = 0; t < T_; ++t) {
        f32x4 acc0 = {}, acc1 = {}, acc2 = {};

        if (t > 0) {
            // ---- row-group barrier: wait all 64 producers of step t-1 ----
            if (w == 0) {
                const int* fp = flags + (((rg << 6) + l) * FLAG_STRIDE);
                while (__hip_atomic_load(fp, __ATOMIC_RELAXED,
                                         __HIP_MEMORY_SCOPE_AGENT) < t) {
                    __builtin_amdgcn_s_sleep(2);
                }
                __builtin_amdgcn_fence(__ATOMIC_ACQUIRE, "agent");
            }
            __syncthreads();

            // ---- issue ALL 32 A-fragment loads (register-resident, in flight) ----
            const f16* __restrict__ ap = hid16 + (long)(t - 1) * (P_ * H_) + arow_base;
            f16x8 areg[16][2];
#pragma unroll
            for (int kk = 0; kk < 16; ++kk) {
                areg[kk][0] = *(const f16x8*)(ap + kk * 64);
                areg[kk][1] = *(const f16x8*)(ap + kk * 64 + 32);
            }

            // ---- K-loop: B from resident LDS, A from registers ----
#pragma unroll
            for (int kk = 0; kk < 16; ++kk) {
#pragma unroll
                for (int sub = 0; sub < 2; ++sub) {
                    f16x8 bf0 = *(const f16x8*)(lds + b_off[0][sub] + kk * 128);
                    f16x8 bf1 = *(const f16x8*)(lds + b_off[1][sub] + kk * 128);
                    f16x8 bf2 = *(const f16x8*)(lds + b_off[2][sub] + kk * 128);
                    acc0 = __builtin_amdgcn_mfma_f32_16x16x32_f16(areg[kk][sub], bf0, acc0, 0, 0, 0);
                    acc1 = __builtin_amdgcn_mfma_f32_16x16x32_f16(areg[kk][sub], bf1, acc1, 0, 0, 0);
                    acc2 = __builtin_amdgcn_mfma_f32_16x16x32_f16(areg[kk][sub], bf2, acc2, 0, 0, 0);
                }
            }
        }
        // t == 0: h = 0 -> gh = bias only (acc stays 0)

        // ---- epilogue: gates + h update (gx in regs, h in regs) ----
        const long toff = (long)t * (P_ * H_);
#pragma unroll
        for (int r = 0; r < 4; ++r) {
            float hr = acc0[r] + bhr;
            float hz = acc1[r] + bhz;
            float hn = acc2[r] + bhn;
            float rr = fast_sig((float)pgr[r] + hr);
            float zz = fast_sig((float)pgz[r] + hz);
            float nn = fast_tanh((float)pgn[r] + rr * hn);
            float hnew = (1.f - zz) * nn + zz * hval[r];
            hval[r] = hnew;
            hid16[toff + dstrow[r]] = (f16)hnew;
        }

        if (t + 1 < T_) {
            // prefetch next step's gx
            const long gxb = (long)(t + 1) * BP * 3072 + col;
#pragma unroll
            for (int r = 0; r < 4; ++r) {
                const long row = gxb + (long)(mrow + r) * 3072;
                pgr[r] = gx16[row];
                pgz[r] = gx16[row + H_];
                pgn[r] = gx16[row + 2 * H_];
            }
        }

        __syncthreads();   // all waves' hid16 stores drained (barrier implies waitcnt)
        if (tid == 0) {
            // release: wbl2 + flag publish (round-4 verified path)
            __hip_atomic_store(flags + (((rg << 6) + nb) * FLAG_STRIDE), t + 1,
                               __ATOMIC_RELEASE, __HIP_MEMORY_SCOPE_AGENT);
        }
    }
}

// ---- per-(b,t): 12x9 action logits, maxpool over P, 8 activity logits ----
__global__ __launch_bounds__(256) void logits_kernel(const f16* __restrict__ hid16,
                                                     const float* __restrict__ W_act,
                                                     const float* __restrict__ b_act,
                                                     const float* __restrict__ W_activ,
                                                     const float* __restrict__ b_activ,
                                                     float* __restrict__ out) {
    __shared__ f16 hs[P_ * H_];
    __shared__ float pooled[H_];
    const int bt = blockIdx.x;           // b*T_ + t
    const int tid = threadIdx.x, w = tid >> 6, l = tid & 63;

    const f16x8* src = (const f16x8*)(hid16 + (long)bt * P_ * H_);
    f16x8* dst = (f16x8*)hs;
    for (int i = tid; i < P_ * H_ / 8; i += 256) dst[i] = src[i];
    __syncthreads();

    for (int i = tid; i < H_; i += 256) {
        float mx = (float)hs[i];
#pragma unroll
        for (int p = 1; p < P_; ++p) mx = fmaxf(mx, (float)hs[p * H_ + i]);
        pooled[i] = mx;
    }
    __syncthreads();

    for (int j = w; j < 108; j += 4) {
        int p = j / 9, a = j % 9;
        float s = 0.f;
#pragma unroll
        for (int it = 0; it < 16; ++it) {
            int idx = l + it * 64;
            s += (float)hs[p * H_ + idx] * W_act[a * H_ + idx];
        }
#pragma unroll
        for (int off = 32; off > 0; off >>= 1) s += __shfl_down(s, off);
        if (l == 0) out[((long)bt * P_ + p) * 9 + a] = s + b_act[a];
    }
    for (int j = w; j < 8; j += 4) {
        float s = 0.f;
#pragma unroll
        for (int it = 0; it < 16; ++it) {
            int idx = l + it * 64;
            s += pooled[idx] * W_activ[j * H_ + idx];
        }
#pragma unroll
        for (int off = 32; off > 0; off >>= 1) s += __shfl_down(s, off);
        if (l == 0) out[(long)M_ * 9 + (long)bt * 8 + j] = s + b_activ[j];
    }
}

extern "C" void kernel_launch(void* const* d_in, const int* in_sizes, int n_in,
                              void* d_out, int out_size, void* d_ws, size_t ws_size,
                              hipStream_t stream) {
    const float* feature = (const float*)d_in[0];
    const float* W_embed = (const float*)d_in[1];
    const float* b_embed = (const float*)d_in[2];
    const float* W_ih    = (const float*)d_in[3];
    const float* W_hh    = (const float*)d_in[4];
    const float* b_ih    = (const float*)d_in[5];
    const float* b_hh    = (const float*)d_in[6];
    const float* W_act   = (const float*)d_in[7];
    const float* b_act   = (const float*)d_in[8];
    const float* W_activ = (const float*)d_in[9];
    const float* b_activ = (const float*)d_in[10];
    float* out = (float*)d_out;

    char* ws = (char*)d_ws;
    size_t off = 0;
    auto alloc = [&](size_t bytes) {
        void* p = ws + off;
        off = (off + bytes + 255) & ~(size_t)255;
        return p;
    };
    f16*   feat16 = (f16*)alloc((size_t)M_ * E_ * 2);
    f16*   wE16   = (f16*)alloc((size_t)H_ * E_ * 2);
    f16*   wIH16  = (f16*)alloc((size_t)3 * H_ * H_ * 2);
    f16*   wHH16  = (f16*)alloc((size_t)3 * H_ * H_ * 2);
    f16*   x16    = (f16*)alloc((size_t)M_ * H_ * 2);
    f16*   gx16   = (f16*)alloc((size_t)M_ * 3 * H_ * 2);
    float* h32    = (float*)alloc((size_t)BP * H_ * 4);
    f16*   h16a   = (f16*)alloc((size_t)BP * H_ * 2);
    f16*   h16b   = (f16*)alloc((size_t)BP * H_ * 2);
    f16*   hid16  = (f16*)alloc((size_t)M_ * H_ * 2);
    // barrier flags alias the (cooperative-path-unused) h32 buffer: 16 KB of 1.5 MB
    int*   flags  = (int*)h32;
    (void)ws_size; (void)in_sizes; (void)n_in; (void)out_size;

    // fp32 -> fp16 packs (single fused launch)
    cvt_all<<<CVT_N3 / 256, 256, 0, stream>>>(feature, W_embed, W_ih, W_hh,
                                              feat16, wE16, wIH16, wHH16);

    // embed: x = tanh(feat @ W_embed^T + b)
    gemm128<0><<<dim3(M_ / 128, H_ / 128), 256, 0, stream>>>(feat16, wE16, b_embed, x16, E_, H_);
    // gx = x @ W_ih^T + b_ih, remapped to [T][BP][3H]
    gemm128<1><<<dim3(M_ / 128, (3 * H_) / 128), 256, 0, stream>>>(x16, wIH16, b_ih, gx16, H_, 3 * H_);

    // zero h32 (= barrier flags for cooperative path; h state for fallback) + h16a
    hipMemsetAsync(h32, 0, (size_t)BP * H_ * 4 + (size_t)BP * H_ * 2, stream);

    // persistent GRU over all T steps (cooperative launch guarantees co-residency,
    // which the spin barrier requires)
    (void)hipFuncSetAttribute(reinterpret_cast<const void*>(gru_persistent),
                              hipFuncAttributeMaxDynamicSharedMemorySize, GRU_LDS);
    const f16* p_whh = wHH16; const float* p_bhh = b_hh; const f16* p_gx = gx16;
    f16* p_hid = hid16; int* p_flags = flags;
    void* kargs[] = {&p_whh, &p_bhh, &p_gx, &p_hid, &p_flags};
    hipError_t cerr = hipLaunchCooperativeKernel(
        reinterpret_cast<const void*>(gru_persistent),
        dim3(GRU_GRID), dim3(GRU_THREADS), kargs, GRU_LDS, stream);
    if (cerr != hipSuccess) {
        // fallback: per-step launches (previous verified path)
        for (int t = 0; t < T_; ++t) {
            const f16* hin = (t & 1) ? h16b : h16a;
            f16* hout = (t & 1) ? h16a : h16b;
            gru_step<<<dim3(BP / 32, H_ / 64), 256, 0, stream>>>(hin, hout, h32, wHH16, b_hh,
                                                                 gx16, hid16, t);
        }
    }

    logits_kernel<<<B_ * T_, 256, 0, stream>>>(hid16, W_act, b_act, W_activ, b_activ, out);
}

// Round 7
// 939.053 us; speedup vs baseline: 1.0838x; 1.0838x over previous
//
#include <hip/hip_runtime.h>
#include <cstdint>

#define B_ 32
#define T_ 40
#define P_ 12
#define E_ 2048
#define H_ 1024
#define BP 384      // B_*P_
#define M_ 15360    // B_*T_*P_

typedef _Float16 f16;
typedef _Float16 f16x8 __attribute__((ext_vector_type(8)));
typedef float f32x4 __attribute__((ext_vector_type(4)));

// ---- async global->LDS, 16B per lane (dest = wave-uniform base + lane*16) ----
__device__ __forceinline__ void cp16(const void* g, void* l) {
    auto gp = (const __attribute__((address_space(1))) uint32_t*)(uintptr_t)g;
    auto lp = (__attribute__((address_space(3))) uint32_t*)(uint32_t)(uintptr_t)l;
    __builtin_amdgcn_global_load_lds(gp, lp, 16, 0, 0);
}

__device__ __forceinline__ float fast_tanh(float x) {
    return 1.f - 2.f / (__expf(2.f * x) + 1.f);
}
__device__ __forceinline__ float fast_sig(float x) {
    return 1.f / (1.f + __expf(-x));
}

// ---- fused fp32 -> fp16 conversion of all four inputs (one launch) ----
#define CVT_N0 ((M_ * E_) / 8)
#define CVT_N1 (CVT_N0 + (H_ * E_) / 8)
#define CVT_N2 (CVT_N1 + (3 * H_ * H_) / 8)
#define CVT_N3 (CVT_N2 + (3 * H_ * H_) / 8)
__global__ __launch_bounds__(256) void cvt_all(const float* __restrict__ f,
                                               const float* __restrict__ we,
                                               const float* __restrict__ wih,
                                               const float* __restrict__ whh,
                                               f16* __restrict__ fo, f16* __restrict__ weo,
                                               f16* __restrict__ wiho, f16* __restrict__ whho) {
    int i = blockIdx.x * 256 + threadIdx.x;
    if (i >= CVT_N3) return;
    const float* src; f16* dst; int j;
    if (i < CVT_N0)      { src = f;   dst = fo;   j = i; }
    else if (i < CVT_N1) { src = we;  dst = weo;  j = i - CVT_N0; }
    else if (i < CVT_N2) { src = wih; dst = wiho; j = i - CVT_N1; }
    else                 { src = whh; dst = whho; j = i - CVT_N2; }
    const float4* in4 = (const float4*)src;
    float4 a = in4[2 * j], b = in4[2 * j + 1];
    f16x8 o = {(f16)a.x, (f16)a.y, (f16)a.z, (f16)a.w,
               (f16)b.x, (f16)b.y, (f16)b.z, (f16)b.w};
    ((f16x8*)dst)[j] = o;
}

// ---- 128x128 tile NT-GEMM, 2-phase double-buffered LDS ----
template <int EPI>
__global__ __launch_bounds__(256) void gemm128(const f16* __restrict__ A,
                                               const f16* __restrict__ Bm,
                                               const float* __restrict__ bias,
                                               f16* __restrict__ out, int K, int N) {
    __shared__ f16 As[2][128 * 32];
    __shared__ f16 Bs[2][128 * 32];
    const int tid = threadIdx.x;
    const int w = tid >> 6, l = tid & 63;
    const int wm = w >> 1, wn = w & 1;      // 2x2 waves of 64x64
    const long arow0 = (long)blockIdx.x * 128;
    const long brow0 = (long)blockIdx.y * 128;
    const int srow = l >> 2, scol = (l & 3) * 8;

    const f16* aptr = A + (arow0 + srow) * (long)K + scol;
    const f16* bptr = Bm + (brow0 + srow) * (long)K + scol;

    f32x4 acc[4][4] = {};

    // prologue: stage tile 0
#pragma unroll
    for (int s = 0; s < 2; ++s) {
        int slice = w + s * 4;              // wave-uniform
        cp16(aptr + (long)slice * 16 * K, (void*)(As[0] + slice * 512));
        cp16(bptr + (long)slice * 16 * K, (void*)(Bs[0] + slice * 512));
    }
    asm volatile("s_waitcnt vmcnt(0)" ::: "memory");
    __syncthreads();

    const int nt = K >> 5;
    for (int t = 0; t < nt; ++t) {
        const int cur = t & 1;
        if (t + 1 < nt) {                   // stage next tile; in flight during MFMA
            const long k0 = (long)(t + 1) << 5;
#pragma unroll
            for (int s = 0; s < 2; ++s) {
                int slice = w + s * 4;
                cp16(aptr + (long)slice * 16 * K + k0, (void*)(As[cur ^ 1] + slice * 512));
                cp16(bptr + (long)slice * 16 * K + k0, (void*)(Bs[cur ^ 1] + slice * 512));
            }
        }
        f16x8 af[4], bf[4];
#pragma unroll
        for (int i = 0; i < 4; ++i)
            af[i] = *(const f16x8*)(As[cur] + (wm * 64 + i * 16 + (l & 15)) * 32 + (l >> 4) * 8);
#pragma unroll
        for (int j = 0; j < 4; ++j)
            bf[j] = *(const f16x8*)(Bs[cur] + (wn * 64 + j * 16 + (l & 15)) * 32 + (l >> 4) * 8);
#pragma unroll
        for (int i = 0; i < 4; ++i)
#pragma unroll
            for (int j = 0; j < 4; ++j)
                acc[i][j] = __builtin_amdgcn_mfma_f32_16x16x32_f16(af[i], bf[j], acc[i][j], 0, 0, 0);
        // one drain+barrier per K-step (next tile's loads complete during compute)
        asm volatile("s_waitcnt vmcnt(0)" ::: "memory");
        __syncthreads();
    }

    const int colq = l & 15, rowq = (l >> 4) * 4;
#pragma unroll
    for (int i = 0; i < 4; ++i)
#pragma unroll
        for (int j = 0; j < 4; ++j)
#pragma unroll
            for (int r = 0; r < 4; ++r) {
                long m = arow0 + wm * 64 + i * 16 + rowq + r;
                int n = (int)brow0 + wn * 64 + j * 16 + colq;
                float v = acc[i][j][r] + bias[n];
                if (EPI == 0) {
                    out[m * N + n] = (f16)fast_tanh(v);
                } else {
                    int b = (int)(m / (T_ * P_));
                    int rem = (int)(m % (T_ * P_));
                    int t = rem / P_, p = rem % P_;
                    out[((long)t * BP + b * P_ + p) * N + n] = (f16)v;
                }
            }
}

// ---- fallback per-step GRU kernel (used only if cooperative launch fails) ----
__global__ __launch_bounds__(256) void gru_step(const f16* __restrict__ h16_in,
                                                f16* __restrict__ h16_out,
                                                float* __restrict__ h32,
                                                const f16* __restrict__ Whh,
                                                const float* __restrict__ b_hh,
                                                const f16* __restrict__ gx16,
                                                f16* __restrict__ hid16, int t) {
    __shared__ f16 As[32 * 32];
    __shared__ f16 Bs[3 * 64 * 32];
    const int tid = threadIdx.x;
    const int w = tid >> 6, l = tid & 63;
    const int m0 = blockIdx.x * 32, n0 = blockIdx.y * 64;
    const int srow = l >> 2, scol = (l & 3) * 8;

    f32x4 acc[3][2] = {};

    for (int k0 = 0; k0 < H_; k0 += 32) {
        __syncthreads();
        if (w < 2)
            cp16(h16_in + (m0 + w * 16 + srow) * H_ + k0 + scol, (void*)(As + w * 512));
#pragma unroll
        for (int q3 = 0; q3 < 3; ++q3) {
            int s = w + q3 * 4;
            int g = s >> 2, q = s & 3;
            cp16(Whh + (long)(g * H_ + n0 + q * 16 + srow) * H_ + k0 + scol,
                 (void*)(Bs + (g * 64 + q * 16) * 32));
        }
        __syncthreads();
        f16x8 af[2], bf[3];
#pragma unroll
        for (int i = 0; i < 2; ++i)
            af[i] = *(const f16x8*)(As + (i * 16 + (l & 15)) * 32 + (l >> 4) * 8);
#pragma unroll
        for (int g = 0; g < 3; ++g)
            bf[g] = *(const f16x8*)(Bs + (g * 64 + w * 16 + (l & 15)) * 32 + (l >> 4) * 8);
#pragma unroll
        for (int g = 0; g < 3; ++g)
#pragma unroll
            for (int i = 0; i < 2; ++i)
                acc[g][i] = __builtin_amdgcn_mfma_f32_16x16x32_f16(af[i], bf[g], acc[g][i], 0, 0, 0);
    }

    const int col = n0 + w * 16 + (l & 15);
    const long gxbase = (long)t * BP * 3072;
    const float bhr = b_hh[col], bhz = b_hh[H_ + col], bhn = b_hh[2 * H_ + col];
#pragma unroll
    for (int i = 0; i < 2; ++i)
#pragma unroll
        for (int r = 0; r < 4; ++r) {
            int m = m0 + i * 16 + (l >> 4) * 4 + r;
            float hr = acc[0][i][r] + bhr;
            float hz = acc[1][i][r] + bhz;
            float hn = acc[2][i][r] + bhn;
            long gxrow = gxbase + (long)m * 3072;
            float xr = (float)gx16[gxrow + col];
            float xz = (float)gx16[gxrow + H_ + col];
            float xn = (float)gx16[gxrow + 2 * H_ + col];
            float rr = fast_sig(xr + hr);
            float zz = fast_sig(xz + hz);
            float nn = fast_tanh(xn + rr * hn);
            float hp = h32[m * H_ + col];
            float hnew = (1.f - zz) * nn + zz * hp;
            h32[m * H_ + col] = hnew;
            h16_out[m * H_ + col] = (f16)hnew;
            int b = m / P_, p = m % P_;
            hid16[(((long)b * T_ + t) * P_ + p) * H_ + col] = (f16)hnew;
        }
}

// ================= persistent GRU: all 40 steps in one cooperative launch =======
// 256 blocks x 384 threads (6 waves, 1 block/CU). Block owns 96 h-rows x 16 h-cols.
// Per-row-group flag barrier (64 producers; release-store publish = round-4
// verified path). A (h) operand loaded DIRECTLY from hid16 into registers in MFMA
// fragment layout; sched_barrier(0) pins all 32 loads ABOVE the MFMA loop so they
// are all in flight (round 6 failed because the scheduler sank them: VGPR=48).
// Consumer side: NO hardware acquire-inv -- every step reads fresh addresses
// (hid16[t-1] written once this launch, never previously cached consumer-side;
// dispatch-boundary cache ops cover cross-replay staleness); the spin uses a
// coherent agent-scope atomic load and in-order issue orders the h loads after it.
#define GRU_GRID 256
#define GRU_THREADS 384
#define GRU_LDS (48 * 1024 * 2)              // 98304 B  W_hh slice only
#define FLAG_STRIDE 16                        // ints; 64B per flag

__global__ __launch_bounds__(GRU_THREADS) void gru_persistent(
        const f16* __restrict__ Whh, const float* __restrict__ bhh,
        const f16* __restrict__ gx16, f16* __restrict__ hid16,
        int* __restrict__ flags) {
    extern __shared__ char lds[];

    const int tid = threadIdx.x;
    const int w = tid >> 6, l = tid & 63;
    const int q = l >> 4;

    // XCD row-affinity: blocks on one XCD (bid&7) share the same 96 h-rows
    const int bid = blockIdx.x;
    const int x = bid & 7;
    const int rg = x >> 1;                        // 0..3 row-group, 2 XCDs each
    const int nb = (x & 1) * 32 + (bid >> 3);     // 0..63 col-group
    const int m0 = rg * 96;
    const int j0 = nb * 16;

    // ---- one-time: W_hh slice -> LDS, swizzled (byte ^= (row&7)<<4) ----
    for (int c = tid; c < 6144; c += GRU_THREADS) {
        int r = c >> 7;                  // local row 0..47 = g*16 + jr
        int kc = (c & 127) * 8;          // f16 col
        int grow = (r >> 4) * H_ + j0 + (r & 15);
        f16x8 v = *(const f16x8*)(Whh + (long)grow * H_ + kc);
        *(f16x8*)(lds + r * 2048 + ((kc * 2) ^ ((r & 7) << 4))) = v;
    }

    // ---- per-thread constant offsets ----
    int b_off[3][2];
#pragma unroll
    for (int sub = 0; sub < 2; ++sub)
#pragma unroll
        for (int g = 0; g < 3; ++g) {
            int br = g * 16 + (l & 15);
            b_off[g][sub] = br * 2048 + (((sub * 32 + q * 8) * 2) ^ ((br & 7) << 4));
        }

    // A-fragment source: this lane reads ONE hid16 row (mA) at cols q*8 + kk*64 + sub*32
    const int mA = m0 + w * 16 + (l & 15);
    const long arow_base = ((long)(mA / P_) * (T_ * P_) + (mA % P_)) * H_ + q * 8;

    const int col = j0 + (l & 15);
    const float bhr = bhh[col], bhz = bhh[H_ + col], bhn = bhh[2 * H_ + col];
    const int mrow = m0 + w * 16 + q * 4;
    // hid16 destination rows for this thread's 4 outputs
    long dstrow[4];
#pragma unroll
    for (int r = 0; r < 4; ++r) {
        int m = mrow + r;
        dstrow[r] = ((long)(m / P_) * T_ * P_ + (m % P_)) * H_ + col;
    }

    // persistent fp32 h state (this thread owns rows mrow..mrow+3 at column col)
    float hval[4] = {0.f, 0.f, 0.f, 0.f};

    // gx prefetch registers for step 0
    f16 pgr[4], pgz[4], pgn[4];
#pragma unroll
    for (int r = 0; r < 4; ++r) {
        const long row = (long)(mrow + r) * 3072 + col;
        pgr[r] = gx16[row];
        pgz[r] = gx16[row + H_];
        pgn[r] = gx16[row + 2 * H_];
    }
    __syncthreads();   // W_hh staged, gx(0) in regs

    for (int t = 0; t < T_; ++t) {
        f32x4 acc0 = {}, acc1 = {}, acc2 = {};

        if (t > 0) {
            // ---- row-group barrier: wait all 64 producers of step t-1 ----
            if (w == 0) {
                const int* fp = flags + (((rg << 6) + l) * FLAG_STRIDE);
                while (__hip_atomic_load(fp, __ATOMIC_RELAXED,
                                         __HIP_MEMORY_SCOPE_AGENT) < t) {
                    __builtin_amdgcn_s_sleep(2);
                }
            }
            __syncthreads();
            asm volatile("" ::: "memory");   // compiler barrier: h loads stay below spin

            // ---- issue ALL 32 A-fragment loads; sched_barrier pins them here ----
            const f16* __restrict__ ap = hid16 + (long)(t - 1) * (P_ * H_) + arow_base;
            f16x8 areg[16][2];
#pragma unroll
            for (int kk = 0; kk < 16; ++kk) {
                areg[kk][0] = *(const f16x8*)(ap + kk * 64);
                areg[kk][1] = *(const f16x8*)(ap + kk * 64 + 32);
            }
            __builtin_amdgcn_sched_barrier(0);   // do NOT sink loads into MFMA loop

            // ---- K-loop: B from resident LDS, A from registers ----
#pragma unroll
            for (int kk = 0; kk < 16; ++kk) {
#pragma unroll
                for (int sub = 0; sub < 2; ++sub) {
                    f16x8 bf0 = *(const f16x8*)(lds + b_off[0][sub] + kk * 128);
                    f16x8 bf1 = *(const f16x8*)(lds + b_off[1][sub] + kk * 128);
                    f16x8 bf2 = *(const f16x8*)(lds + b_off[2][sub] + kk * 128);
                    acc0 = __builtin_amdgcn_mfma_f32_16x16x32_f16(areg[kk][sub], bf0, acc0, 0, 0, 0);
                    acc1 = __builtin_amdgcn_mfma_f32_16x16x32_f16(areg[kk][sub], bf1, acc1, 0, 0, 0);
                    acc2 = __builtin_amdgcn_mfma_f32_16x16x32_f16(areg[kk][sub], bf2, acc2, 0, 0, 0);
                }
            }
        }
        // t == 0: h = 0 -> gh = bias only (acc stays 0)

        // ---- epilogue: gates + h update (gx in regs, h in regs) ----
        const long toff = (long)t * (P_ * H_);
#pragma unroll
        for (int r = 0; r < 4; ++r) {
            float hr = acc0[r] + bhr;
            float hz = acc1[r] + bhz;
            float hn = acc2[r] + bhn;
            float rr = fast_sig((float)pgr[r] + hr);
            float zz = fast_sig((float)pgz[r] + hz);
            float nn = fast_tanh((float)pgn[r] + rr * hn);
            float hnew = (1.f - zz) * nn + zz * hval[r];
            hval[r] = hnew;
            hid16[toff + dstrow[r]] = (f16)hnew;
        }

        if (t + 1 < T_) {
            // prefetch next step's gx
            const long gxb = (long)(t + 1) * BP * 3072 + col;
#pragma unroll
            for (int r = 0; r < 4; ++r) {
                const long row = gxb + (long)(mrow + r) * 3072;
                pgr[r] = gx16[row];
                pgz[r] = gx16[row + H_];
                pgn[r] = gx16[row + 2 * H_];
            }
        }

        __syncthreads();   // all waves' hid16 stores drained (barrier implies waitcnt)
        if (tid == 0) {
            // release: wbl2 + flag publish (round-4 verified path)
            __hip_atomic_store(flags + (((rg << 6) + nb) * FLAG_STRIDE), t + 1,
                               __ATOMIC_RELEASE, __HIP_MEMORY_SCOPE_AGENT);
        }
    }
}

// ---- per-(b,t): 12x9 action logits, maxpool over P, 8 activity logits ----
__global__ __launch_bounds__(256) void logits_kernel(const f16* __restrict__ hid16,
                                                     const float* __restrict__ W_act,
                                                     const float* __restrict__ b_act,
                                                     const float* __restrict__ W_activ,
                                                     const float* __restrict__ b_activ,
                                                     float* __restrict__ out) {
    __shared__ f16 hs[P_ * H_];
    __shared__ float pooled[H_];
    const int bt = blockIdx.x;           // b*T_ + t
    const int tid = threadIdx.x, w = tid >> 6, l = tid & 63;

    const f16x8* src = (const f16x8*)(hid16 + (long)bt * P_ * H_);
    f16x8* dst = (f16x8*)hs;
    for (int i = tid; i < P_ * H_ / 8; i += 256) dst[i] = src[i];
    __syncthreads();

    for (int i = tid; i < H_; i += 256) {
        float mx = (float)hs[i];
#pragma unroll
        for (int p = 1; p < P_; ++p) mx = fmaxf(mx, (float)hs[p * H_ + i]);
        pooled[i] = mx;
    }
    __syncthreads();

    for (int j = w; j < 108; j += 4) {
        int p = j / 9, a = j % 9;
        float s = 0.f;
#pragma unroll
        for (int it = 0; it < 16; ++it) {
            int idx = l + it * 64;
            s += (float)hs[p * H_ + idx] * W_act[a * H_ + idx];
        }
#pragma unroll
        for (int off = 32; off > 0; off >>= 1) s += __shfl_down(s, off);
        if (l == 0) out[((long)bt * P_ + p) * 9 + a] = s + b_act[a];
    }
    for (int j = w; j < 8; j += 4) {
        float s = 0.f;
#pragma unroll
        for (int it = 0; it < 16; ++it) {
            int idx = l + it * 64;
            s += pooled[idx] * W_activ[j * H_ + idx];
        }
#pragma unroll
        for (int off = 32; off > 0; off >>= 1) s += __shfl_down(s, off);
        if (l == 0) out[(long)M_ * 9 + (long)bt * 8 + j] = s + b_activ[j];
    }
}

extern "C" void kernel_launch(void* const* d_in, const int* in_sizes, int n_in,
                              void* d_out, int out_size, void* d_ws, size_t ws_size,
                              hipStream_t stream) {
    const float* feature = (const float*)d_in[0];
    const float* W_embed = (const float*)d_in[1];
    const float* b_embed = (const float*)d_in[2];
    const float* W_ih    = (const float*)d_in[3];
    const float* W_hh    = (const float*)d_in[4];
    const float* b_ih    = (const float*)d_in[5];
    const float* b_hh    = (const float*)d_in[6];
    const float* W_act   = (const float*)d_in[7];
    const float* b_act   = (const float*)d_in[8];
    const float* W_activ = (const float*)d_in[9];
    const float* b_activ = (const float*)d_in[10];
    float* out = (float*)d_out;

    char* ws = (char*)d_ws;
    size_t off = 0;
    auto alloc = [&](size_t bytes) {
        void* p = ws + off;
        off = (off + bytes + 255) & ~(size_t)255;
        return p;
    };
    f16*   feat16 = (f16*)alloc((size_t)M_ * E_ * 2);
    f16*   wE16   = (f16*)alloc((size_t)H_ * E_ * 2);
    f16*   wIH16  = (f16*)alloc((size_t)3 * H_ * H_ * 2);
    f16*   wHH16  = (f16*)alloc((size_t)3 * H_ * H_ * 2);
    f16*   x16    = (f16*)alloc((size_t)M_ * H_ * 2);
    f16*   gx16   = (f16*)alloc((size_t)M_ * 3 * H_ * 2);
    float* h32    = (float*)alloc((size_t)BP * H_ * 4);
    f16*   h16a   = (f16*)alloc((size_t)BP * H_ * 2);
    f16*   h16b   = (f16*)alloc((size_t)BP * H_ * 2);
    f16*   hid16  = (f16*)alloc((size_t)M_ * H_ * 2);
    // barrier flags alias the (cooperative-path-unused) h32 buffer: 16 KB of 1.5 MB
    int*   flags  = (int*)h32;
    (void)ws_size; (void)in_sizes; (void)n_in; (void)out_size;

    // fp32 -> fp16 packs (single fused launch)
    cvt_all<<<CVT_N3 / 256, 256, 0, stream>>>(feature, W_embed, W_ih, W_hh,
                                              feat16, wE16, wIH16, wHH16);

    // embed: x = tanh(feat @ W_embed^T + b)
    gemm128<0><<<dim3(M_ / 128, H_ / 128), 256, 0, stream>>>(feat16, wE16, b_embed, x16, E_, H_);
    // gx = x @ W_ih^T + b_ih, remapped to [T][BP][3H]
    gemm128<1><<<dim3(M_ / 128, (3 * H_) / 128), 256, 0, stream>>>(x16, wIH16, b_ih, gx16, H_, 3 * H_);

    // zero h32 (= barrier flags for cooperative path; h state for fallback) + h16a
    hipMemsetAsync(h32, 0, (size_t)BP * H_ * 4 + (size_t)BP * H_ * 2, stream);

    // persistent GRU over all T steps (cooperative launch guarantees co-residency,
    // which the spin barrier requires)
    (void)hipFuncSetAttribute(reinterpret_cast<const void*>(gru_persistent),
                              hipFuncAttributeMaxDynamicSharedMemorySize, GRU_LDS);
    const f16* p_whh = wHH16; const float* p_bhh = b_hh; const f16* p_gx = gx16;
    f16* p_hid = hid16; int* p_flags = flags;
    void* kargs[] = {&p_whh, &p_bhh, &p_gx, &p_hid, &p_flags};
    hipError_t cerr = hipLaunchCooperativeKernel(
        reinterpret_cast<const void*>(gru_persistent),
        dim3(GRU_GRID), dim3(GRU_THREADS), kargs, GRU_LDS, stream);
    if (cerr != hipSuccess) {
        // fallback: per-step launches (previous verified path)
        for (int t = 0; t < T_; ++t) {
            const f16* hin = (t & 1) ? h16b : h16a;
            f16* hout = (t & 1) ? h16a : h16b;
            gru_step<<<dim3(BP / 32, H_ / 64), 256, 0, stream>>>(hin, hout, h32, wHH16, b_hh,
                                                                 gx16, hid16, t);
        }
    }

    logits_kernel<<<B_ * T_, 256, 0, stream>>>(hid16, W_act, b_act, W_activ, b_activ, out);
}

// Round 8
// 857.250 us; speedup vs baseline: 1.1872x; 1.0954x over previous
//
#include <hip/hip_runtime.h>
#include <cstdint>

#define B_ 32
#define T_ 40
#define P_ 12
#define E_ 2048
#define H_ 1024
#define BP 384      // B_*P_
#define M_ 15360    // B_*T_*P_

typedef _Float16 f16;
typedef _Float16 f16x8 __attribute__((ext_vector_type(8)));
typedef float f32x4 __attribute__((ext_vector_type(4)));

// ---- async global->LDS, 16B per lane (dest = wave-uniform base + lane*16) ----
__device__ __forceinline__ void cp16(const void* g, void* l) {
    auto gp = (const __attribute__((address_space(1))) uint32_t*)(uintptr_t)g;
    auto lp = (__attribute__((address_space(3))) uint32_t*)(uint32_t)(uintptr_t)l;
    __builtin_amdgcn_global_load_lds(gp, lp, 16, 0, 0);
}

// ---- write-through 2B store: data goes to the coherence point (no dirty L2
// line). vmcnt-retire of this store => globally visible. Round-5-verified encoding.
__device__ __forceinline__ void store_wt(f16* p, f16 v) {
    unsigned short u = __builtin_bit_cast(unsigned short, v);
    asm volatile("global_store_short %0, %1, off sc0 sc1" :: "v"(p), "v"(u) : "memory");
}

__device__ __forceinline__ float fast_tanh(float x) {
    return 1.f - 2.f / (__expf(2.f * x) + 1.f);
}
__device__ __forceinline__ float fast_sig(float x) {
    return 1.f / (1.f + __expf(-x));
}

// ---- fused fp32 -> fp16 conversion of all four inputs (one launch) ----
#define CVT_N0 ((M_ * E_) / 8)
#define CVT_N1 (CVT_N0 + (H_ * E_) / 8)
#define CVT_N2 (CVT_N1 + (3 * H_ * H_) / 8)
#define CVT_N3 (CVT_N2 + (3 * H_ * H_) / 8)
__global__ __launch_bounds__(256) void cvt_all(const float* __restrict__ f,
                                               const float* __restrict__ we,
                                               const float* __restrict__ wih,
                                               const float* __restrict__ whh,
                                               f16* __restrict__ fo, f16* __restrict__ weo,
                                               f16* __restrict__ wiho, f16* __restrict__ whho) {
    int i = blockIdx.x * 256 + threadIdx.x;
    if (i >= CVT_N3) return;
    const float* src; f16* dst; int j;
    if (i < CVT_N0)      { src = f;   dst = fo;   j = i; }
    else if (i < CVT_N1) { src = we;  dst = weo;  j = i - CVT_N0; }
    else if (i < CVT_N2) { src = wih; dst = wiho; j = i - CVT_N1; }
    else                 { src = whh; dst = whho; j = i - CVT_N2; }
    const float4* in4 = (const float4*)src;
    float4 a = in4[2 * j], b = in4[2 * j + 1];
    f16x8 o = {(f16)a.x, (f16)a.y, (f16)a.z, (f16)a.w,
               (f16)b.x, (f16)b.y, (f16)b.z, (f16)b.w};
    ((f16x8*)dst)[j] = o;
}

// ---- 128x128 tile NT-GEMM, 2-phase double-buffered LDS ----
template <int EPI>
__global__ __launch_bounds__(256) void gemm128(const f16* __restrict__ A,
                                               const f16* __restrict__ Bm,
                                               const float* __restrict__ bias,
                                               f16* __restrict__ out, int K, int N) {
    __shared__ f16 As[2][128 * 32];
    __shared__ f16 Bs[2][128 * 32];
    const int tid = threadIdx.x;
    const int w = tid >> 6, l = tid & 63;
    const int wm = w >> 1, wn = w & 1;      // 2x2 waves of 64x64
    const long arow0 = (long)blockIdx.x * 128;
    const long brow0 = (long)blockIdx.y * 128;
    const int srow = l >> 2, scol = (l & 3) * 8;

    const f16* aptr = A + (arow0 + srow) * (long)K + scol;
    const f16* bptr = Bm + (brow0 + srow) * (long)K + scol;

    f32x4 acc[4][4] = {};

    // prologue: stage tile 0
#pragma unroll
    for (int s = 0; s < 2; ++s) {
        int slice = w + s * 4;              // wave-uniform
        cp16(aptr + (long)slice * 16 * K, (void*)(As[0] + slice * 512));
        cp16(bptr + (long)slice * 16 * K, (void*)(Bs[0] + slice * 512));
    }
    asm volatile("s_waitcnt vmcnt(0)" ::: "memory");
    __syncthreads();

    const int nt = K >> 5;
    for (int t = 0; t < nt; ++t) {
        const int cur = t & 1;
        if (t + 1 < nt) {                   // stage next tile; in flight during MFMA
            const long k0 = (long)(t + 1) << 5;
#pragma unroll
            for (int s = 0; s < 2; ++s) {
                int slice = w + s * 4;
                cp16(aptr + (long)slice * 16 * K + k0, (void*)(As[cur ^ 1] + slice * 512));
                cp16(bptr + (long)slice * 16 * K + k0, (void*)(Bs[cur ^ 1] + slice * 512));
            }
        }
        f16x8 af[4], bf[4];
#pragma unroll
        for (int i = 0; i < 4; ++i)
            af[i] = *(const f16x8*)(As[cur] + (wm * 64 + i * 16 + (l & 15)) * 32 + (l >> 4) * 8);
#pragma unroll
        for (int j = 0; j < 4; ++j)
            bf[j] = *(const f16x8*)(Bs[cur] + (wn * 64 + j * 16 + (l & 15)) * 32 + (l >> 4) * 8);
#pragma unroll
        for (int i = 0; i < 4; ++i)
#pragma unroll
            for (int j = 0; j < 4; ++j)
                acc[i][j] = __builtin_amdgcn_mfma_f32_16x16x32_f16(af[i], bf[j], acc[i][j], 0, 0, 0);
        // one drain+barrier per K-step (next tile's loads complete during compute)
        asm volatile("s_waitcnt vmcnt(0)" ::: "memory");
        __syncthreads();
    }

    const int colq = l & 15, rowq = (l >> 4) * 4;
#pragma unroll
    for (int i = 0; i < 4; ++i)
#pragma unroll
        for (int j = 0; j < 4; ++j)
#pragma unroll
            for (int r = 0; r < 4; ++r) {
                long m = arow0 + wm * 64 + i * 16 + rowq + r;
                int n = (int)brow0 + wn * 64 + j * 16 + colq;
                float v = acc[i][j][r] + bias[n];
                if (EPI == 0) {
                    out[m * N + n] = (f16)fast_tanh(v);
                } else {
                    int b = (int)(m / (T_ * P_));
                    int rem = (int)(m % (T_ * P_));
                    int t = rem / P_, p = rem % P_;
                    out[((long)t * BP + b * P_ + p) * N + n] = (f16)v;
                }
            }
}

// ---- fallback per-step GRU kernel (used only if cooperative launch fails) ----
__global__ __launch_bounds__(256) void gru_step(const f16* __restrict__ h16_in,
                                                f16* __restrict__ h16_out,
                                                float* __restrict__ h32,
                                                const f16* __restrict__ Whh,
                                                const float* __restrict__ b_hh,
                                                const f16* __restrict__ gx16,
                                                f16* __restrict__ hid16, int t) {
    __shared__ f16 As[32 * 32];
    __shared__ f16 Bs[3 * 64 * 32];
    const int tid = threadIdx.x;
    const int w = tid >> 6, l = tid & 63;
    const int m0 = blockIdx.x * 32, n0 = blockIdx.y * 64;
    const int srow = l >> 2, scol = (l & 3) * 8;

    f32x4 acc[3][2] = {};

    for (int k0 = 0; k0 < H_; k0 += 32) {
        __syncthreads();
        if (w < 2)
            cp16(h16_in + (m0 + w * 16 + srow) * H_ + k0 + scol, (void*)(As + w * 512));
#pragma unroll
        for (int q3 = 0; q3 < 3; ++q3) {
            int s = w + q3 * 4;
            int g = s >> 2, q = s & 3;
            cp16(Whh + (long)(g * H_ + n0 + q * 16 + srow) * H_ + k0 + scol,
                 (void*)(Bs + (g * 64 + q * 16) * 32));
        }
        __syncthreads();
        f16x8 af[2], bf[3];
#pragma unroll
        for (int i = 0; i < 2; ++i)
            af[i] = *(const f16x8*)(As + (i * 16 + (l & 15)) * 32 + (l >> 4) * 8);
#pragma unroll
        for (int g = 0; g < 3; ++g)
            bf[g] = *(const f16x8*)(Bs + (g * 64 + w * 16 + (l & 15)) * 32 + (l >> 4) * 8);
#pragma unroll
        for (int g = 0; g < 3; ++g)
#pragma unroll
            for (int i = 0; i < 2; ++i)
                acc[g][i] = __builtin_amdgcn_mfma_f32_16x16x32_f16(af[i], bf[g], acc[g][i], 0, 0, 0);
    }

    const int col = n0 + w * 16 + (l & 15);
    const long gxbase = (long)t * BP * 3072;
    const float bhr = b_hh[col], bhz = b_hh[H_ + col], bhn = b_hh[2 * H_ + col];
#pragma unroll
    for (int i = 0; i < 2; ++i)
#pragma unroll
        for (int r = 0; r < 4; ++r) {
            int m = m0 + i * 16 + (l >> 4) * 4 + r;
            float hr = acc[0][i][r] + bhr;
            float hz = acc[1][i][r] + bhz;
            float hn = acc[2][i][r] + bhn;
            long gxrow = gxbase + (long)m * 3072;
            float xr = (float)gx16[gxrow + col];
            float xz = (float)gx16[gxrow + H_ + col];
            float xn = (float)gx16[gxrow + 2 * H_ + col];
            float rr = fast_sig(xr + hr);
            float zz = fast_sig(xz + hz);
            float nn = fast_tanh(xn + rr * hn);
            float hp = h32[m * H_ + col];
            float hnew = (1.f - zz) * nn + zz * hp;
            h32[m * H_ + col] = hnew;
            h16_out[m * H_ + col] = (f16)hnew;
            int b = m / P_, p = m % P_;
            hid16[(((long)b * T_ + t) * P_ + p) * H_ + col] = (f16)hnew;
        }
}

// ================= persistent GRU: all 40 steps in one cooperative launch =======
// 256 blocks x 384 threads (6 waves, 1 block/CU). Block owns 96 h-rows x 16 h-cols.
// Per-row-group flag barrier (64 producers). This round: h published with
// WRITE-THROUGH stores + explicit vmcnt(0) drain (data at coherence point at
// retire), so the flag publish is a RELAXED agent store -- no buffer_wbl2 L2
// sweep in the critical path (the round 4-7 release-store paid it every step).
// gx prefetch moved AFTER the flag publish so its latency no longer delays the
// flag (it overlaps the next spin instead). Consumer side unchanged from round 7
// (no inv: fresh addresses each step; same-XCD wt copies are clean/current).
#define GRU_GRID 256
#define GRU_THREADS 384
#define GRU_LDS (48 * 1024 * 2)              // 98304 B  W_hh slice only
#define FLAG_STRIDE 16                        // ints; 64B per flag

__global__ __launch_bounds__(GRU_THREADS) void gru_persistent(
        const f16* __restrict__ Whh, const float* __restrict__ bhh,
        const f16* __restrict__ gx16, f16* __restrict__ hid16,
        int* __restrict__ flags) {
    extern __shared__ char lds[];

    const int tid = threadIdx.x;
    const int w = tid >> 6, l = tid & 63;
    const int q = l >> 4;

    // XCD row-affinity: blocks on one XCD (bid&7) share the same 96 h-rows
    const int bid = blockIdx.x;
    const int x = bid & 7;
    const int rg = x >> 1;                        // 0..3 row-group, 2 XCDs each
    const int nb = (x & 1) * 32 + (bid >> 3);     // 0..63 col-group
    const int m0 = rg * 96;
    const int j0 = nb * 16;

    // ---- one-time: W_hh slice -> LDS, swizzled (byte ^= (row&7)<<4) ----
    for (int c = tid; c < 6144; c += GRU_THREADS) {
        int r = c >> 7;                  // local row 0..47 = g*16 + jr
        int kc = (c & 127) * 8;          // f16 col
        int grow = (r >> 4) * H_ + j0 + (r & 15);
        f16x8 v = *(const f16x8*)(Whh + (long)grow * H_ + kc);
        *(f16x8*)(lds + r * 2048 + ((kc * 2) ^ ((r & 7) << 4))) = v;
    }

    // ---- per-thread constant offsets ----
    int b_off[3][2];
#pragma unroll
    for (int sub = 0; sub < 2; ++sub)
#pragma unroll
        for (int g = 0; g < 3; ++g) {
            int br = g * 16 + (l & 15);
            b_off[g][sub] = br * 2048 + (((sub * 32 + q * 8) * 2) ^ ((br & 7) << 4));
        }

    // A-fragment source: this lane reads ONE hid16 row (mA) at cols q*8 + kk*64 + sub*32
    const int mA = m0 + w * 16 + (l & 15);
    const long arow_base = ((long)(mA / P_) * (T_ * P_) + (mA % P_)) * H_ + q * 8;

    const int col = j0 + (l & 15);
    const float bhr = bhh[col], bhz = bhh[H_ + col], bhn = bhh[2 * H_ + col];
    const int mrow = m0 + w * 16 + q * 4;
    // hid16 destination rows for this thread's 4 outputs
    long dstrow[4];
#pragma unroll
    for (int r = 0; r < 4; ++r) {
        int m = mrow + r;
        dstrow[r] = ((long)(m / P_) * T_ * P_ + (m % P_)) * H_ + col;
    }

    // persistent fp32 h state (this thread owns rows mrow..mrow+3 at column col)
    float hval[4] = {0.f, 0.f, 0.f, 0.f};

    // gx prefetch registers for step 0
    f16 pgr[4], pgz[4], pgn[4];
#pragma unroll
    for (int r = 0; r < 4; ++r) {
        const long row = (long)(mrow + r) * 3072 + col;
        pgr[r] = gx16[row];
        pgz[r] = gx16[row + H_];
        pgn[r] = gx16[row + 2 * H_];
    }
    __syncthreads();   // W_hh staged, gx(0) in regs

    for (int t = 0; t < T_; ++t) {
        f32x4 acc0 = {}, acc1 = {}, acc2 = {};

        if (t > 0) {
            // ---- row-group barrier: wait all 64 producers of step t-1 ----
            if (w == 0) {
                const int* fp = flags + (((rg << 6) + l) * FLAG_STRIDE);
                while (__hip_atomic_load(fp, __ATOMIC_RELAXED,
                                         __HIP_MEMORY_SCOPE_AGENT) < t) {
                    __builtin_amdgcn_s_sleep(2);
                }
            }
            __syncthreads();
            asm volatile("" ::: "memory");   // compiler barrier: h loads stay below spin

            // ---- issue ALL 32 A-fragment loads; sched_barrier pins them here ----
            const f16* __restrict__ ap = hid16 + (long)(t - 1) * (P_ * H_) + arow_base;
            f16x8 areg[16][2];
#pragma unroll
            for (int kk = 0; kk < 16; ++kk) {
                areg[kk][0] = *(const f16x8*)(ap + kk * 64);
                areg[kk][1] = *(const f16x8*)(ap + kk * 64 + 32);
            }
            __builtin_amdgcn_sched_barrier(0);   // do NOT sink loads into MFMA loop

            // ---- K-loop: B from resident LDS, A from registers ----
#pragma unroll
            for (int kk = 0; kk < 16; ++kk) {
#pragma unroll
                for (int sub = 0; sub < 2; ++sub) {
                    f16x8 bf0 = *(const f16x8*)(lds + b_off[0][sub] + kk * 128);
                    f16x8 bf1 = *(const f16x8*)(lds + b_off[1][sub] + kk * 128);
                    f16x8 bf2 = *(const f16x8*)(lds + b_off[2][sub] + kk * 128);
                    acc0 = __builtin_amdgcn_mfma_f32_16x16x32_f16(areg[kk][sub], bf0, acc0, 0, 0, 0);
                    acc1 = __builtin_amdgcn_mfma_f32_16x16x32_f16(areg[kk][sub], bf1, acc1, 0, 0, 0);
                    acc2 = __builtin_amdgcn_mfma_f32_16x16x32_f16(areg[kk][sub], bf2, acc2, 0, 0, 0);
                }
            }
        }
        // t == 0: h = 0 -> gh = bias only (acc stays 0)

        // ---- epilogue: gates + h update; publish h write-through ----
        const long toff = (long)t * (P_ * H_);
#pragma unroll
        for (int r = 0; r < 4; ++r) {
            float hr = acc0[r] + bhr;
            float hz = acc1[r] + bhz;
            float hn = acc2[r] + bhn;
            float rr = fast_sig((float)pgr[r] + hr);
            float zz = fast_sig((float)pgz[r] + hz);
            float nn = fast_tanh((float)pgn[r] + rr * hn);
            float hnew = (1.f - zz) * nn + zz * hval[r];
            hval[r] = hnew;
            store_wt(hid16 + toff + dstrow[r], (f16)hnew);
        }
        // drain wt stores: retire => at coherence point (asm stores are outside
        // compiler tracking, so the barrier below would not necessarily wait)
        asm volatile("s_waitcnt vmcnt(0)" ::: "memory");
        __syncthreads();   // all 384 threads' h stores globally visible
        if (tid == 0) {
            // RELAXED publish: no wbl2 sweep (wt already pushed data down)
            __hip_atomic_store(flags + (((rg << 6) + nb) * FLAG_STRIDE), t + 1,
                               __ATOMIC_RELAXED, __HIP_MEMORY_SCOPE_AGENT);
        }

        if (t + 1 < T_) {
            // prefetch next step's gx AFTER the flag publish: latency overlaps
            // the next spin instead of delaying the flag store
            const long gxb = (long)(t + 1) * BP * 3072 + col;
#pragma unroll
            for (int r = 0; r < 4; ++r) {
                const long row = gxb + (long)(mrow + r) * 3072;
                pgr[r] = gx16[row];
                pgz[r] = gx16[row + H_];
                pgn[r] = gx16[row + 2 * H_];
            }
        }
    }
}

// ---- per-(b,t): 12x9 action logits, maxpool over P, 8 activity logits ----
__global__ __launch_bounds__(256) void logits_kernel(const f16* __restrict__ hid16,
                                                     const float* __restrict__ W_act,
                                                     const float* __restrict__ b_act,
                                                     const float* __restrict__ W_activ,
                                                     const float* __restrict__ b_activ,
                                                     float* __restrict__ out) {
    __shared__ f16 hs[P_ * H_];
    __shared__ float pooled[H_];
    const int bt = blockIdx.x;           // b*T_ + t
    const int tid = threadIdx.x, w = tid >> 6, l = tid & 63;

    const f16x8* src = (const f16x8*)(hid16 + (long)bt * P_ * H_);
    f16x8* dst = (f16x8*)hs;
    for (int i = tid; i < P_ * H_ / 8; i += 256) dst[i] = src[i];
    __syncthreads();

    for (int i = tid; i < H_; i += 256) {
        float mx = (float)hs[i];
#pragma unroll
        for (int p = 1; p < P_; ++p) mx = fmaxf(mx, (float)hs[p * H_ + i]);
        pooled[i] = mx;
    }
    __syncthreads();

    for (int j = w; j < 108; j += 4) {
        int p = j / 9, a = j % 9;
        float s = 0.f;
#pragma unroll
        for (int it = 0; it < 16; ++it) {
            int idx = l + it * 64;
            s += (float)hs[p * H_ + idx] * W_act[a * H_ + idx];
        }
#pragma unroll
        for (int off = 32; off > 0; off >>= 1) s += __shfl_down(s, off);
        if (l == 0) out[((long)bt * P_ + p) * 9 + a] = s + b_act[a];
    }
    for (int j = w; j < 8; j += 4) {
        float s = 0.f;
#pragma unroll
        for (int it = 0; it < 16; ++it) {
            int idx = l + it * 64;
            s += pooled[idx] * W_activ[j * H_ + idx];
        }
#pragma unroll
        for (int off = 32; off > 0; off >>= 1) s += __shfl_down(s, off);
        if (l == 0) out[(long)M_ * 9 + (long)bt * 8 + j] = s + b_activ[j];
    }
}

extern "C" void kernel_launch(void* const* d_in, const int* in_sizes, int n_in,
                              void* d_out, int out_size, void* d_ws, size_t ws_size,
                              hipStream_t stream) {
    const float* feature = (const float*)d_in[0];
    const float* W_embed = (const float*)d_in[1];
    const float* b_embed = (const float*)d_in[2];
    const float* W_ih    = (const float*)d_in[3];
    const float* W_hh    = (const float*)d_in[4];
    const float* b_ih    = (const float*)d_in[5];
    const float* b_hh    = (const float*)d_in[6];
    const float* W_act   = (const float*)d_in[7];
    const float* b_act   = (const float*)d_in[8];
    const float* W_activ = (const float*)d_in[9];
    const float* b_activ = (const float*)d_in[10];
    float* out = (float*)d_out;

    char* ws = (char*)d_ws;
    size_t off = 0;
    auto alloc = [&](size_t bytes) {
        void* p = ws + off;
        off = (off + bytes + 255) & ~(size_t)255;
        return p;
    };
    f16*   feat16 = (f16*)alloc((size_t)M_ * E_ * 2);
    f16*   wE16   = (f16*)alloc((size_t)H_ * E_ * 2);
    f16*   wIH16  = (f16*)alloc((size_t)3 * H_ * H_ * 2);
    f16*   wHH16  = (f16*)alloc((size_t)3 * H_ * H_ * 2);
    f16*   x16    = (f16*)alloc((size_t)M_ * H_ * 2);
    f16*   gx16   = (f16*)alloc((size_t)M_ * 3 * H_ * 2);
    float* h32    = (float*)alloc((size_t)BP * H_ * 4);
    f16*   h16a   = (f16*)alloc((size_t)BP * H_ * 2);
    f16*   h16b   = (f16*)alloc((size_t)BP * H_ * 2);
    f16*   hid16  = (f16*)alloc((size_t)M_ * H_ * 2);
    // barrier flags alias the (cooperative-path-unused) h32 buffer: 16 KB of 1.5 MB
    int*   flags  = (int*)h32;
    (void)ws_size; (void)in_sizes; (void)n_in; (void)out_size;

    // fp32 -> fp16 packs (single fused launch)
    cvt_all<<<CVT_N3 / 256, 256, 0, stream>>>(feature, W_embed, W_ih, W_hh,
                                              feat16, wE16, wIH16, wHH16);

    // embed: x = tanh(feat @ W_embed^T + b)
    gemm128<0><<<dim3(M_ / 128, H_ / 128), 256, 0, stream>>>(feat16, wE16, b_embed, x16, E_, H_);
    // gx = x @ W_ih^T + b_ih, remapped to [T][BP][3H]
    gemm128<1><<<dim3(M_ / 128, (3 * H_) / 128), 256, 0, stream>>>(x16, wIH16, b_ih, gx16, H_, 3 * H_);

    // zero h32 (= barrier flags for cooperative path; h state for fallback) + h16a
    hipMemsetAsync(h32, 0, (size_t)BP * H_ * 4 + (size_t)BP * H_ * 2, stream);

    // persistent GRU over all T steps (cooperative launch guarantees co-residency,
    // which the spin barrier requires)
    (void)hipFuncSetAttribute(reinterpret_cast<const void*>(gru_persistent),
                              hipFuncAttributeMaxDynamicSharedMemorySize, GRU_LDS);
    const f16* p_whh = wHH16; const float* p_bhh = b_hh; const f16* p_gx = gx16;
    f16* p_hid = hid16; int* p_flags = flags;
    void* kargs[] = {&p_whh, &p_bhh, &p_gx, &p_hid, &p_flags};
    hipError_t cerr = hipLaunchCooperativeKernel(
        reinterpret_cast<const void*>(gru_persistent),
        dim3(GRU_GRID), dim3(GRU_THREADS), kargs, GRU_LDS, stream);
    if (cerr != hipSuccess) {
        // fallback: per-step launches (previous verified path)
        for (int t = 0; t < T_; ++t) {
            const f16* hin = (t & 1) ? h16b : h16a;
            f16* hout = (t & 1) ? h16a : h16b;
            gru_step<<<dim3(BP / 32, H_ / 64), 256, 0, stream>>>(hin, hout, h32, wHH16, b_hh,
                                                                 gx16, hid16, t);
        }
    }

    logits_kernel<<<B_ * T_, 256, 0, stream>>>(hid16, W_act, b_act, W_activ, b_activ, out);
}